// Round 1
// baseline (358.578 us; speedup 1.0000x reference)
//
#include <hip/hip_runtime.h>
#include <hip/hip_bf16.h>
#include <math.h>

// B=4096, IN=1024, H=2048, OUT=1024, DEPTH=8
//
// Key simplification: _cosmic_processing(cw,...) == broadcast of
//   prob[r] = (1/H) * ( prod_{d=0..7} prod_{k=0..2} cos(cw[d,r,k]) )^2
// because s0 is constant along axis=1 and the roll-update preserves that
// (-si*v + si*v cancels exactly), leaving s *= cos each substep.
//
// Network = 6 GEMMs (fp16 MFMA, fp32 accum) with fused epilogues.

typedef _Float16 f16;
typedef _Float16 f16x8 __attribute__((ext_vector_type(8)));
typedef _Float16 f16x4 __attribute__((ext_vector_type(4)));
typedef float f32x4 __attribute__((ext_vector_type(4)));

#define GLD16(gp, lp) __builtin_amdgcn_global_load_lds( \
    (const __attribute__((address_space(1))) unsigned int*)(gp), \
    (__attribute__((address_space(3))) unsigned int*)(lp), 16, 0, 0)

// ---------------- fp32 -> fp16 cast (vectorized) ----------------
__global__ void cast_f32_f16(const float* __restrict__ in, f16* __restrict__ out, int n4) {
  int i = blockIdx.x * 256 + threadIdx.x;
  if (i < n4) {
    float4 v = ((const float4*)in)[i];
    f16x4 o = { (f16)v.x, (f16)v.y, (f16)v.z, (f16)v.w };
    ((f16x4*)out)[i] = o;
  }
}

// ---------------- cast + transpose: W (K,N) f32 -> WT (N,K) f16 ----------------
__global__ void cast_transpose(const float* __restrict__ W, f16* __restrict__ WT, int K, int N) {
  __shared__ float tile[32][33];
  int bx = blockIdx.x * 32;   // N dim
  int by = blockIdx.y * 32;   // K dim
  int tx = threadIdx.x & 31;
  int ty = threadIdx.x >> 5;  // 0..7
#pragma unroll
  for (int r = ty; r < 32; r += 8)
    tile[r][tx] = W[(size_t)(by + r) * N + bx + tx];
  __syncthreads();
#pragma unroll
  for (int r = ty; r < 32; r += 8)
    WT[(size_t)(bx + r) * K + by + tx] = (f16)tile[tx][r];
}

// ---------------- cosmic prob vector ----------------
__global__ void cosmic_prob(const float* __restrict__ cw, float* __restrict__ prob, int H) {
  int r = blockIdx.x * 256 + threadIdx.x;
  if (r >= H) return;
  float p = 1.0f;
#pragma unroll
  for (int d = 0; d < 8; ++d) {
    const float* a = cw + ((size_t)d * H + r) * H;  // cw[d, r, 0..2]
    p *= cosf(a[0]) * cosf(a[1]) * cosf(a[2]);
  }
  prob[r] = p * p / (float)H;
}

// ---------------- fp16 MFMA GEMM, 128x128 tile, BK=32, 4 waves ----------------
// A: (M,K) row-major f16.  BT: (N,K) row-major f16 (i.e. B transposed).
// EPI=0: relu(acc + bias[col]) -> f16
// EPI=1: tanh(acc + bias[col] + prob[col]) -> f16
// EPI=2: relu(acc + bias[col]) -> f32 (final output)
template <int EPI>
__global__ __launch_bounds__(256)
void gemm_f16(const f16* __restrict__ A, const f16* __restrict__ BT,
              const float* __restrict__ bias, const float* __restrict__ prob,
              f16* __restrict__ Ch, float* __restrict__ Cf,
              int M, int N, int K) {
  __shared__ f16 As[128 * 32];
  __shared__ f16 Bs[128 * 32];

  const int t = threadIdx.x;
  const int m0 = blockIdx.y * 128;
  const int n0 = blockIdx.x * 128;
  const int wave = t >> 6;
  const int lane = t & 63;
  const int wr = wave >> 1, wc = wave & 1;   // 2x2 waves -> 64x64 each
  const int kg = lane >> 4, rc = lane & 15;

  // staging: flat f16 index f = t*8 covers rows [0,64) of a [128][32] tile;
  // second issue (+2048) covers rows [64,128). LDS dest is linear => matches
  // global_load_lds wave-uniform-base + lane*16 semantics.
  const int fA = t * 8;
  const int rowA = fA >> 5;
  const int colA = fA & 31;
  const f16* ag0 = A + (size_t)(m0 + rowA) * K + colA;
  const f16* ag1 = ag0 + (size_t)64 * K;
  const f16* bg0 = BT + (size_t)(n0 + rowA) * K + colA;
  const f16* bg1 = bg0 + (size_t)64 * K;

  f32x4 acc[4][4] = {};

  for (int k0 = 0; k0 < K; k0 += 32) {
    GLD16(ag0 + k0, As + fA);
    GLD16(ag1 + k0, As + fA + 2048);
    GLD16(bg0 + k0, Bs + fA);
    GLD16(bg1 + k0, Bs + fA + 2048);
    __syncthreads();  // drains vmcnt before barrier (compiler-inserted)

    f16x8 af[4], bf[4];
#pragma unroll
    for (int i = 0; i < 4; ++i)
      af[i] = *(const f16x8*)&As[(wr * 64 + i * 16 + rc) * 32 + kg * 8];
#pragma unroll
    for (int n = 0; n < 4; ++n)
      bf[n] = *(const f16x8*)&Bs[(wc * 64 + n * 16 + rc) * 32 + kg * 8];

#pragma unroll
    for (int i = 0; i < 4; ++i)
#pragma unroll
      for (int n = 0; n < 4; ++n)
        acc[i][n] = __builtin_amdgcn_mfma_f32_16x16x32_f16(af[i], bf[n], acc[i][n], 0, 0, 0);
    __syncthreads();
  }

  // epilogue: C/D layout col=lane&15, row=(lane>>4)*4+q  [m89-verified]
#pragma unroll
  for (int n = 0; n < 4; ++n) {
    const int col = n0 + wc * 64 + n * 16 + rc;
    float bn = bias[col];
    if (EPI == 1) bn += prob[col];
#pragma unroll
    for (int i = 0; i < 4; ++i) {
      const int row = m0 + wr * 64 + i * 16 + kg * 4;
#pragma unroll
      for (int q = 0; q < 4; ++q) {
        float v = acc[i][n][q] + bn;
        if (EPI == 1) v = tanhf(v);
        else v = fmaxf(v, 0.0f);
        if (EPI == 2) Cf[(size_t)(row + q) * N + col] = v;
        else Ch[(size_t)(row + q) * N + col] = (f16)v;
      }
    }
  }
}

extern "C" void kernel_launch(void* const* d_in, const int* in_sizes, int n_in,
                              void* d_out, int out_size, void* d_ws, size_t ws_size,
                              hipStream_t stream) {
  const float* x   = (const float*)d_in[0];
  const float* W0  = (const float*)d_in[1];
  const float* b0  = (const float*)d_in[2];
  const float* W1  = (const float*)d_in[3];
  const float* b1  = (const float*)d_in[4];
  const float* cw1 = (const float*)d_in[5];
  /* d_in[6] = cb1 unused by reference */
  const float* KW1 = (const float*)d_in[7];
  const float* Kb1 = (const float*)d_in[8];
  const float* W2  = (const float*)d_in[9];
  const float* b2  = (const float*)d_in[10];
  const float* cw2 = (const float*)d_in[11];
  /* d_in[12] = cb2 unused */
  const float* KW2 = (const float*)d_in[13];
  const float* Kb2 = (const float*)d_in[14];
  const float* W3  = (const float*)d_in[15];
  const float* b3  = (const float*)d_in[16];

  const int B = 4096, IN = 1024, H = 2048, OUT = 1024;

  char* ws = (char*)d_ws;
  size_t off = 0;
  auto alloc = [&](size_t bytes) {
    char* p = ws + off;
    off = (off + bytes + 255) & ~(size_t)255;
    return p;
  };
  f16* xh    = (f16*)alloc((size_t)B * IN * 2);
  f16* W0T   = (f16*)alloc((size_t)H * IN * 2);
  f16* W1T   = (f16*)alloc((size_t)H * H * 2);
  f16* KW1T  = (f16*)alloc((size_t)H * H * 2);
  f16* W2T   = (f16*)alloc((size_t)H * H * 2);
  f16* KW2T  = (f16*)alloc((size_t)H * H * 2);
  f16* W3T   = (f16*)alloc((size_t)OUT * H * 2);
  f16* hA    = (f16*)alloc((size_t)B * H * 2);
  f16* hB    = (f16*)alloc((size_t)B * H * 2);
  float* p1  = (float*)alloc((size_t)H * 4);
  float* p2  = (float*)alloc((size_t)H * 4);
  (void)ws_size;

  // prep: casts, transposes, cosmic vectors
  cast_f32_f16<<<(B * IN / 4 + 255) / 256, 256, 0, stream>>>(x, xh, B * IN / 4);
  cast_transpose<<<dim3(H / 32, IN / 32), 256, 0, stream>>>(W0, W0T, IN, H);
  cast_transpose<<<dim3(H / 32, H / 32), 256, 0, stream>>>(W1, W1T, H, H);
  cast_transpose<<<dim3(H / 32, H / 32), 256, 0, stream>>>(KW1, KW1T, H, H);
  cast_transpose<<<dim3(H / 32, H / 32), 256, 0, stream>>>(W2, W2T, H, H);
  cast_transpose<<<dim3(H / 32, H / 32), 256, 0, stream>>>(KW2, KW2T, H, H);
  cast_transpose<<<dim3(OUT / 32, H / 32), 256, 0, stream>>>(W3, W3T, H, OUT);
  cosmic_prob<<<(H + 255) / 256, 256, 0, stream>>>(cw1, p1, H);
  cosmic_prob<<<(H + 255) / 256, 256, 0, stream>>>(cw2, p2, H);

  // h1 = relu(x @ W0 + b0)
  gemm_f16<0><<<dim3(H / 128, B / 128), 256, 0, stream>>>(xh, W0T, b0, nullptr, hA, nullptr, B, H, IN);
  // h2 = relu(h1 @ W1 + b1)
  gemm_f16<0><<<dim3(H / 128, B / 128), 256, 0, stream>>>(hA, W1T, b1, nullptr, hB, nullptr, B, H, H);
  // h3 = tanh(h2 @ KW1 + Kb1 + prob1)
  gemm_f16<1><<<dim3(H / 128, B / 128), 256, 0, stream>>>(hB, KW1T, Kb1, p1, hA, nullptr, B, H, H);
  // h4 = relu(h3 @ W2 + b2)
  gemm_f16<0><<<dim3(H / 128, B / 128), 256, 0, stream>>>(hA, W2T, b2, nullptr, hB, nullptr, B, H, H);
  // h5 = tanh(h4 @ KW2 + Kb2 + prob2)
  gemm_f16<1><<<dim3(H / 128, B / 128), 256, 0, stream>>>(hB, KW2T, Kb2, p2, hA, nullptr, B, H, H);
  // out = relu(h5 @ W3 + b3) -> f32
  gemm_f16<2><<<dim3(OUT / 128, B / 128), 256, 0, stream>>>(hA, W3T, b3, nullptr, nullptr, (float*)d_out, B, OUT, H);
}

// Round 2
// 249.908 us; speedup vs baseline: 1.4348x; 1.4348x over previous
//
#include <hip/hip_runtime.h>
#include <math.h>

// B=4096, IN=1024, H=2048, OUT=1024
// cosmic layer == broadcast prob[r] = (1/H)*(prod cos(cw[d,r,k]))^2  (roll terms cancel)
// Network = 6 fp16-MFMA GEMMs with fused bias/relu/tanh epilogues.
//
// GEMM: BM=256 x BN=128, BK=64, 512 thr (8 waves 4Mx2N, 64x64/wave),
// tri-buffered LDS (144 KB), counted vmcnt(6) (T4), XOR-swizzled LDS (T2),
// setprio around MFMA (T5), XCD-aware block swizzle (T1).

typedef _Float16 f16;
typedef _Float16 f16x8 __attribute__((ext_vector_type(8)));
typedef _Float16 f16x4 __attribute__((ext_vector_type(4)));
typedef float f32x4 __attribute__((ext_vector_type(4)));

#define GLD16(gp, lp) __builtin_amdgcn_global_load_lds( \
    (const __attribute__((address_space(1))) unsigned int*)(gp), \
    (__attribute__((address_space(3))) unsigned int*)(lp), 16, 0, 0)

// ---------------- fp32 -> fp16 cast ----------------
__global__ void cast_f32_f16(const float* __restrict__ in, f16* __restrict__ out, int n4) {
  int i = blockIdx.x * 256 + threadIdx.x;
  if (i < n4) {
    float4 v = ((const float4*)in)[i];
    f16x4 o = { (f16)v.x, (f16)v.y, (f16)v.z, (f16)v.w };
    ((f16x4*)out)[i] = o;
  }
}

// ---------------- merged cast+transpose for all 6 weights ----------------
struct TD { const float* src; f16* dst; int K; int N; };
struct TD6 { TD d[6]; };

__global__ void cast_transpose6(TD6 a) {
  TD d = a.d[blockIdx.z];
  int bx = blockIdx.x * 32, by = blockIdx.y * 32;
  if (bx >= d.N || by >= d.K) return;
  __shared__ float tile[32][33];
  int tx = threadIdx.x & 31, ty = threadIdx.x >> 5;
#pragma unroll
  for (int r = ty; r < 32; r += 8)
    tile[r][tx] = d.src[(size_t)(by + r) * d.N + bx + tx];
  __syncthreads();
#pragma unroll
  for (int r = ty; r < 32; r += 8)
    d.dst[(size_t)(bx + r) * d.K + by + tx] = (f16)tile[tx][r];
}

// ---------------- cosmic prob vector ----------------
__global__ void cosmic_prob(const float* __restrict__ cw, float* __restrict__ prob, int H) {
  int r = blockIdx.x * 256 + threadIdx.x;
  if (r >= H) return;
  float p = 1.0f;
#pragma unroll
  for (int d = 0; d < 8; ++d) {
    const float* a = cw + ((size_t)d * H + r) * H;
    p *= cosf(a[0]) * cosf(a[1]) * cosf(a[2]);
  }
  prob[r] = p * p / (float)H;
}

// ---------------- fp16 MFMA GEMM ----------------
// A: (M,K) f16 row-major. BT: (N,K) f16 row-major.
// EPI 0: relu->f16  1: tanh(+prob)->f16  2: relu->f32
template <int EPI>
__global__ __launch_bounds__(512, 2)
void gemm_f16(const f16* __restrict__ A, const f16* __restrict__ BT,
              const float* __restrict__ bias, const float* __restrict__ prob,
              f16* __restrict__ Ch, float* __restrict__ Cf,
              int M, int N, int K, int GX) {
  // LDS: A 3x[256][64] f16, B 3x[128][64] f16  -> 144 KiB
  __shared__ f16 lds[3 * 16384 + 3 * 8192];
  f16* As = lds;
  f16* Bs = lds + 3 * 16384;

  const int t = threadIdx.x;

  // XCD-aware swizzle: 8 XCDs, contiguous chunk per XCD (nwg % 8 == 0)
  const int nwg = gridDim.x;
  const int bid = blockIdx.x;
  const int swz = (bid & 7) * (nwg >> 3) + (bid >> 3);
  const int bx = swz % GX;
  const int by = swz / GX;
  const int m0 = by * 256;
  const int n0 = bx * 128;

  // stage one K-tile (A: 4 rounds, B: 2 rounds of 512x16B).
  // LDS dest is LINEAR (wave-uniform base + lane*16); the XOR swizzle
  // (chunk ^= row&7) is applied to the GLOBAL source address (rule 21).
  auto stage = [&](int kt, int buf) {
    const int k0 = kt << 6;
#pragma unroll
    for (int q = 0; q < 4; ++q) {
      int Fh = q * 4096 + t * 8;          // f16 units
      int r = Fh >> 6;
      int c = (Fh >> 3) & 7;
      const f16* src = A + (size_t)(m0 + r) * K + k0 + ((c ^ (r & 7)) << 3);
      GLD16(src, As + buf * 16384 + Fh);
    }
#pragma unroll
    for (int q = 0; q < 2; ++q) {
      int Fh = q * 4096 + t * 8;
      int r = Fh >> 6;
      int c = (Fh >> 3) & 7;
      const f16* src = BT + (size_t)(n0 + r) * K + k0 + ((c ^ (r & 7)) << 3);
      GLD16(src, Bs + buf * 8192 + Fh);
    }
  };

  const int wave = t >> 6, lane = t & 63;
  const int wr = wave >> 1, wc = wave & 1;   // 4M x 2N waves -> 64x64 each
  const int kg = lane >> 4, rc = lane & 15;

  f32x4 acc[4][4] = {};

  auto compute = [&](int buf) {
    const f16* Ab = As + buf * 16384;
    const f16* Bb = Bs + buf * 8192;
    f16x8 af[2][4], bf[2][4];
#pragma unroll
    for (int s = 0; s < 2; ++s) {
      const int cc = s * 4 + kg;
#pragma unroll
      for (int i = 0; i < 4; ++i) {
        int row = wr * 64 + i * 16 + rc;
        af[s][i] = *(const f16x8*)&Ab[row * 64 + ((cc ^ (row & 7)) << 3)];
      }
#pragma unroll
      for (int n = 0; n < 4; ++n) {
        int row = wc * 64 + n * 16 + rc;
        bf[s][n] = *(const f16x8*)&Bb[row * 64 + ((cc ^ (row & 7)) << 3)];
      }
    }
    __builtin_amdgcn_s_setprio(1);
#pragma unroll
    for (int s = 0; s < 2; ++s)
#pragma unroll
      for (int i = 0; i < 4; ++i)
#pragma unroll
        for (int n = 0; n < 4; ++n)
          acc[i][n] = __builtin_amdgcn_mfma_f32_16x16x32_f16(af[s][i], bf[s][n], acc[i][n], 0, 0, 0);
    __builtin_amdgcn_s_setprio(0);
  };

  const int nt = K >> 6;
  stage(0, 0);
  stage(1, 1);
  int cur = 0;
  for (int kt = 0; kt < nt - 1; ++kt) {
    // own tile-kt loads retired (oldest 6 of <=12); tiles kt+1(,kt+2) stay in flight
    asm volatile("s_waitcnt vmcnt(6) lgkmcnt(0)" ::: "memory");
    __builtin_amdgcn_s_barrier();
    if (kt + 2 < nt) {
      int sb = cur + 2; if (sb >= 3) sb -= 3;
      stage(kt + 2, sb);                    // overwrites buf last read at kt-1: safe post-barrier
    }
    compute(cur);
    cur = (cur + 1 == 3) ? 0 : cur + 1;
  }
  asm volatile("s_waitcnt vmcnt(0) lgkmcnt(0)" ::: "memory");
  __builtin_amdgcn_s_barrier();
  compute(cur);

  // epilogue: C/D layout col=lane&15, row=(lane>>4)*4+q
#pragma unroll
  for (int n = 0; n < 4; ++n) {
    const int col = n0 + wc * 64 + n * 16 + rc;
    float bn = bias[col];
    if (EPI == 1) bn += prob[col];
#pragma unroll
    for (int i = 0; i < 4; ++i) {
      const int row = m0 + wr * 64 + i * 16 + kg * 4;
#pragma unroll
      for (int q = 0; q < 4; ++q) {
        float v = acc[i][n][q] + bn;
        if (EPI == 1) v = tanhf(v);
        else v = fmaxf(v, 0.0f);
        if (EPI == 2) Cf[(size_t)(row + q) * N + col] = v;
        else Ch[(size_t)(row + q) * N + col] = (f16)v;
      }
    }
  }
}

extern "C" void kernel_launch(void* const* d_in, const int* in_sizes, int n_in,
                              void* d_out, int out_size, void* d_ws, size_t ws_size,
                              hipStream_t stream) {
  const float* x   = (const float*)d_in[0];
  const float* W0  = (const float*)d_in[1];
  const float* b0  = (const float*)d_in[2];
  const float* W1  = (const float*)d_in[3];
  const float* b1  = (const float*)d_in[4];
  const float* cw1 = (const float*)d_in[5];
  const float* KW1 = (const float*)d_in[7];
  const float* Kb1 = (const float*)d_in[8];
  const float* W2  = (const float*)d_in[9];
  const float* b2  = (const float*)d_in[10];
  const float* cw2 = (const float*)d_in[11];
  const float* KW2 = (const float*)d_in[13];
  const float* Kb2 = (const float*)d_in[14];
  const float* W3  = (const float*)d_in[15];
  const float* b3  = (const float*)d_in[16];

  const int B = 4096, IN = 1024, H = 2048, OUT = 1024;

  char* ws = (char*)d_ws;
  size_t off = 0;
  auto alloc = [&](size_t bytes) {
    char* p = ws + off;
    off = (off + bytes + 255) & ~(size_t)255;
    return p;
  };
  f16* xh    = (f16*)alloc((size_t)B * IN * 2);
  f16* W0T   = (f16*)alloc((size_t)H * IN * 2);
  f16* W1T   = (f16*)alloc((size_t)H * H * 2);
  f16* KW1T  = (f16*)alloc((size_t)H * H * 2);
  f16* W2T   = (f16*)alloc((size_t)H * H * 2);
  f16* KW2T  = (f16*)alloc((size_t)H * H * 2);
  f16* W3T   = (f16*)alloc((size_t)OUT * H * 2);
  f16* hA    = (f16*)alloc((size_t)B * H * 2);
  f16* hB    = (f16*)alloc((size_t)B * H * 2);
  float* p1  = (float*)alloc((size_t)H * 4);
  float* p2  = (float*)alloc((size_t)H * 4);
  (void)ws_size;

  cast_f32_f16<<<(B * IN / 4 + 255) / 256, 256, 0, stream>>>(x, xh, B * IN / 4);

  TD6 td;
  td.d[0] = { W0,  W0T,  IN, H };
  td.d[1] = { W1,  W1T,  H,  H };
  td.d[2] = { KW1, KW1T, H,  H };
  td.d[3] = { W2,  W2T,  H,  H };
  td.d[4] = { KW2, KW2T, H,  H };
  td.d[5] = { W3,  W3T,  H,  OUT };
  cast_transpose6<<<dim3(H / 32, H / 32, 6), 256, 0, stream>>>(td);

  cosmic_prob<<<(H + 255) / 256, 256, 0, stream>>>(cw1, p1, H);
  cosmic_prob<<<(H + 255) / 256, 256, 0, stream>>>(cw2, p2, H);

  // grid: 1-D (nwg), kernel derives (bx,by) via XCD swizzle; GX = N/128
  auto launch = [&](int epi, const f16* Aq, const f16* BTq, const float* bi,
                    const float* pr, f16* Co, float* Cfo, int N_, int K_) {
    int gx = N_ / 128, gy = B / 256;
    dim3 grid(gx * gy);
    if (epi == 0) gemm_f16<0><<<grid, 512, 0, stream>>>(Aq, BTq, bi, pr, Co, Cfo, B, N_, K_, gx);
    else if (epi == 1) gemm_f16<1><<<grid, 512, 0, stream>>>(Aq, BTq, bi, pr, Co, Cfo, B, N_, K_, gx);
    else gemm_f16<2><<<grid, 512, 0, stream>>>(Aq, BTq, bi, pr, Co, Cfo, B, N_, K_, gx);
  };

  launch(0, xh, W0T, b0,  nullptr, hA, nullptr, H,   IN);   // h1 = relu(x@W0+b0)
  launch(0, hA, W1T, b1,  nullptr, hB, nullptr, H,   H);    // h2 = relu(h1@W1+b1)
  launch(1, hB, KW1T, Kb1, p1,     hA, nullptr, H,   H);    // h3 = tanh(h2@KW1+Kb1+p1)
  launch(0, hA, W2T, b2,  nullptr, hB, nullptr, H,   H);    // h4 = relu(h3@W2+b2)
  launch(1, hB, KW2T, Kb2, p2,     hA, nullptr, H,   H);    // h5 = tanh(h4@KW2+Kb2+p2)
  launch(2, hA, W3T, b3,  nullptr, nullptr, (float*)d_out, OUT, H); // out = relu(h5@W3+b3)
}

// Round 3
// 234.236 us; speedup vs baseline: 1.5308x; 1.0669x over previous
//
#include <hip/hip_runtime.h>
#include <math.h>

// B=4096, IN=1024, H=2048, OUT=1024
// cosmic layer == broadcast prob[r] = (1/H)*(prod_{d,k} cos(cw[d,r,k]))^2
// Network = 6 fp16-MFMA GEMMs (32x32x16) with fused bias/relu/tanh epilogues.
//
// GEMM: BM x 128 tile (BM=256 main / 128 for the N=1024 GEMM), BK=64,
// 512 thr (8 waves 4Mx2N), tri-buffered LDS, counted vmcnt (T4),
// 4 phases per K-tile with interleaved stage-issue + lgkmcnt(0) +
// sched_barrier (T3, rule 18), setprio around MFMA (T5),
// XOR-swizzled LDS both-sides (T2, rule 21), XCD swizzle (T1).

typedef _Float16 f16;
typedef _Float16 f16x8 __attribute__((ext_vector_type(8)));
typedef _Float16 f16x4 __attribute__((ext_vector_type(4)));
typedef float f32x16 __attribute__((ext_vector_type(16)));

#define GLD16(gp, lp) __builtin_amdgcn_global_load_lds( \
    (const __attribute__((address_space(1))) unsigned int*)(gp), \
    (__attribute__((address_space(3))) unsigned int*)(lp), 16, 0, 0)

// ---------------- fp32 -> fp16 cast ----------------
__global__ void cast_f32_f16(const float* __restrict__ in, f16* __restrict__ out, int n4) {
  int i = blockIdx.x * 256 + threadIdx.x;
  if (i < n4) {
    float4 v = ((const float4*)in)[i];
    f16x4 o = { (f16)v.x, (f16)v.y, (f16)v.z, (f16)v.w };
    ((f16x4*)out)[i] = o;
  }
}

// ---------------- merged cast+transpose for all 6 weights ----------------
struct TD { const float* src; f16* dst; int K; int N; };
struct TD6 { TD d[6]; };

__global__ void cast_transpose6(TD6 a) {
  TD d = a.d[blockIdx.z];
  int bx = blockIdx.x * 32, by = blockIdx.y * 32;
  if (bx >= d.N || by >= d.K) return;
  __shared__ float tile[32][33];
  int tx = threadIdx.x & 31, ty = threadIdx.x >> 5;
#pragma unroll
  for (int r = ty; r < 32; r += 8)
    tile[r][tx] = d.src[(size_t)(by + r) * d.N + bx + tx];
  __syncthreads();
#pragma unroll
  for (int r = ty; r < 32; r += 8)
    d.dst[(size_t)(bx + r) * d.K + by + tx] = (f16)tile[tx][r];
}

// ---------------- cosmic prob, 2-pass ----------------
__global__ void cosmic_pp(const float* __restrict__ cw, float* __restrict__ pp, int H) {
  int i = blockIdx.x * 256 + threadIdx.x;   // i = d*H + r
  if (i >= 8 * H) return;
  const float* a = cw + (size_t)i * H;      // cw[d][r][0..2]
  pp[i] = cosf(a[0]) * cosf(a[1]) * cosf(a[2]);
}
__global__ void cosmic_fin(const float* __restrict__ pp, float* __restrict__ prob, int H) {
  int r = blockIdx.x * 256 + threadIdx.x;
  if (r >= H) return;
  float p = 1.0f;
#pragma unroll
  for (int d = 0; d < 8; ++d) p *= pp[d * H + r];
  prob[r] = p * p / (float)H;
}

// ---------------- fp16 MFMA GEMM (32x32x16) ----------------
// A: (M,K) f16 row-major. BT: (N,K) f16 row-major.
// EPI 0: relu->f16  1: tanh(+prob)->f16  2: relu->f32
template <int EPI, int BM>
__global__ __launch_bounds__(512, 2)
void gemm_f16(const f16* __restrict__ A, const f16* __restrict__ BT,
              const float* __restrict__ bias, const float* __restrict__ prob,
              f16* __restrict__ Ch, float* __restrict__ Cf,
              int M, int N, int K, int GX) {
  constexpr int ASZ = BM * 64;          // f16 per A buffer
  constexpr int BSZ = 128 * 64;         // f16 per B buffer
  constexpr int MB  = BM / 128;         // 32-row frags per wave (2 or 1)
  constexpr int RA  = BM / 64;          // A stage rounds (4 or 2)
  __shared__ f16 lds[3 * (ASZ + BSZ)];
  f16* As = lds;
  f16* Bs = lds + 3 * ASZ;

  const int t = threadIdx.x;

  // XCD-aware swizzle (nwg % 8 == 0 for all our grids)
  const int nwg = gridDim.x;
  const int bid = blockIdx.x;
  const int swz = (bid & 7) * (nwg >> 3) + (bid >> 3);
  const int bx = swz % GX;
  const int by = swz / GX;
  const int m0 = by * BM;
  const int n0 = bx * 128;

  // staging: LDS dest linear (wave-uniform base + lane*16); XOR swizzle
  // (chunk ^= row&7) applied to the GLOBAL source (rule 21).
  auto stageA = [&](int kt, int buf, int q) {
    int F = q * 4096 + t * 8;           // f16 units
    int r = F >> 6, c = (F >> 3) & 7;
    const f16* src = A + (size_t)(m0 + r) * K + (kt << 6) + ((c ^ (r & 7)) << 3);
    GLD16(src, As + buf * ASZ + F);
  };
  auto stageB = [&](int kt, int buf, int q) {
    int F = q * 4096 + t * 8;
    int r = F >> 6, c = (F >> 3) & 7;
    const f16* src = BT + (size_t)(n0 + r) * K + (kt << 6) + ((c ^ (r & 7)) << 3);
    GLD16(src, Bs + buf * BSZ + F);
  };
  auto stage_all = [&](int kt, int buf) {
#pragma unroll
    for (int q = 0; q < RA; ++q) stageA(kt, buf, q);
#pragma unroll
    for (int q = 0; q < 2; ++q) stageB(kt, buf, q);
  };

  const int wave = t >> 6, lane = t & 63;
  const int wr = wave >> 1, wc = wave & 1;  // 4M x 2N waves
  const int rc = lane & 31, hi = lane >> 5;

  f32x16 acc[MB][2] = {};

  // one k-16 phase: 2*MB+... ds_reads, stage-issue slice, lgkm drain, MFMA
  auto kphase = [&](int cur, int p, int stage_kt, int sb) {
    const f16* Ab = As + cur * ASZ;
    const f16* Bb = Bs + cur * BSZ;
    const int cc = p * 2 + hi;          // 16B chunk index (8 f16 each)
    f16x8 a[MB], b[2];
#pragma unroll
    for (int mb = 0; mb < MB; ++mb) {
      int row = wr * (BM / 4) + mb * 32 + rc;
      a[mb] = *(const f16x8*)&Ab[row * 64 + ((cc ^ (row & 7)) << 3)];
    }
#pragma unroll
    for (int nb = 0; nb < 2; ++nb) {
      int row = wc * 64 + nb * 32 + rc;
      b[nb] = *(const f16x8*)&Bb[row * 64 + ((cc ^ (row & 7)) << 3)];
    }
    if (stage_kt >= 0) {
      if (BM == 256) {
        stageA(stage_kt, sb, p);
        if (p < 2) stageB(stage_kt, sb, p);
      } else {
        if (p < 2) stageA(stage_kt, sb, p);
        else stageB(stage_kt, sb, p - 2);
      }
    }
    asm volatile("s_waitcnt lgkmcnt(0)" ::: "memory");
    __builtin_amdgcn_sched_barrier(0);
    __builtin_amdgcn_s_setprio(1);
#pragma unroll
    for (int mb = 0; mb < MB; ++mb)
#pragma unroll
      for (int nb = 0; nb < 2; ++nb)
        acc[mb][nb] = __builtin_amdgcn_mfma_f32_32x32x16_f16(a[mb], b[nb], acc[mb][nb], 0, 0, 0);
    __builtin_amdgcn_s_setprio(0);
    __builtin_amdgcn_sched_barrier(0);
  };

  const int nt = K >> 6;
  stage_all(0, 0);
  stage_all(1, 1);
  int cur = 0;
  for (int kt = 0; kt < nt; ++kt) {
    if (kt + 1 < nt) {
      // tile kt's loads retired; tile kt+1's stay in flight
      if (BM == 256) asm volatile("s_waitcnt vmcnt(6)" ::: "memory");
      else           asm volatile("s_waitcnt vmcnt(4)" ::: "memory");
    } else {
      asm volatile("s_waitcnt vmcnt(0)" ::: "memory");
    }
    __builtin_amdgcn_s_barrier();
    int sb = cur + 2; if (sb >= 3) sb -= 3;
    const int skt = (kt + 2 < nt) ? (kt + 2) : -1;
#pragma unroll
    for (int p = 0; p < 4; ++p) kphase(cur, p, skt, sb);
    cur = (cur + 1 == 3) ? 0 : cur + 1;
  }

  // epilogue: 32x32 C/D layout col=lane&31, row=(r&3)+8*(r>>2)+4*(lane>>5)
#pragma unroll
  for (int nb = 0; nb < 2; ++nb) {
    const int col = n0 + wc * 64 + nb * 32 + rc;
    float bn = bias[col];
    if (EPI == 1) bn += prob[col];
#pragma unroll
    for (int mb = 0; mb < MB; ++mb) {
      const int rbase = m0 + wr * (BM / 4) + mb * 32 + 4 * hi;
#pragma unroll
      for (int r = 0; r < 16; ++r) {
        const int row = rbase + (r & 3) + 8 * (r >> 2);
        float v = acc[mb][nb][r] + bn;
        if (EPI == 1) v = tanhf(v);
        else v = fmaxf(v, 0.0f);
        if (EPI == 2) Cf[(size_t)row * N + col] = v;
        else Ch[(size_t)row * N + col] = (f16)v;
      }
    }
  }
}

extern "C" void kernel_launch(void* const* d_in, const int* in_sizes, int n_in,
                              void* d_out, int out_size, void* d_ws, size_t ws_size,
                              hipStream_t stream) {
  const float* x   = (const float*)d_in[0];
  const float* W0  = (const float*)d_in[1];
  const float* b0  = (const float*)d_in[2];
  const float* W1  = (const float*)d_in[3];
  const float* b1  = (const float*)d_in[4];
  const float* cw1 = (const float*)d_in[5];
  const float* KW1 = (const float*)d_in[7];
  const float* Kb1 = (const float*)d_in[8];
  const float* W2  = (const float*)d_in[9];
  const float* b2  = (const float*)d_in[10];
  const float* cw2 = (const float*)d_in[11];
  const float* KW2 = (const float*)d_in[13];
  const float* Kb2 = (const float*)d_in[14];
  const float* W3  = (const float*)d_in[15];
  const float* b3  = (const float*)d_in[16];

  const int B = 4096, IN = 1024, H = 2048, OUT = 1024;

  char* ws = (char*)d_ws;
  size_t off = 0;
  auto alloc = [&](size_t bytes) {
    char* p = ws + off;
    off = (off + bytes + 255) & ~(size_t)255;
    return p;
  };
  f16* xh    = (f16*)alloc((size_t)B * IN * 2);
  f16* W0T   = (f16*)alloc((size_t)H * IN * 2);
  f16* W1T   = (f16*)alloc((size_t)H * H * 2);
  f16* KW1T  = (f16*)alloc((size_t)H * H * 2);
  f16* W2T   = (f16*)alloc((size_t)H * H * 2);
  f16* KW2T  = (f16*)alloc((size_t)H * H * 2);
  f16* W3T   = (f16*)alloc((size_t)OUT * H * 2);
  f16* hA    = (f16*)alloc((size_t)B * H * 2);
  f16* hB    = (f16*)alloc((size_t)B * H * 2);
  float* p1  = (float*)alloc((size_t)H * 4);
  float* p2  = (float*)alloc((size_t)H * 4);
  float* pp  = (float*)alloc((size_t)8 * H * 4);
  (void)ws_size;

  cast_f32_f16<<<(B * IN / 4 + 255) / 256, 256, 0, stream>>>(x, xh, B * IN / 4);

  TD6 td;
  td.d[0] = { W0,  W0T,  IN, H };
  td.d[1] = { W1,  W1T,  H,  H };
  td.d[2] = { KW1, KW1T, H,  H };
  td.d[3] = { W2,  W2T,  H,  H };
  td.d[4] = { KW2, KW2T, H,  H };
  td.d[5] = { W3,  W3T,  H,  OUT };
  cast_transpose6<<<dim3(H / 32, H / 32, 6), 256, 0, stream>>>(td);

  cosmic_pp<<<(8 * H + 255) / 256, 256, 0, stream>>>(cw1, pp, H);
  cosmic_fin<<<(H + 255) / 256, 256, 0, stream>>>(pp, p1, H);
  cosmic_pp<<<(8 * H + 255) / 256, 256, 0, stream>>>(cw2, pp, H);
  cosmic_fin<<<(H + 255) / 256, 256, 0, stream>>>(pp, p2, H);

  // G0-G4: BM=256 (grid 256). G5: BM=128 (grid 256).
  {
    int gx = H / 128, gy = B / 256;
    dim3 g(gx * gy);
    gemm_f16<0, 256><<<g, 512, 0, stream>>>(xh, W0T, b0,  nullptr, hA, nullptr, B, H, IN, gx);
    gemm_f16<0, 256><<<g, 512, 0, stream>>>(hA, W1T, b1,  nullptr, hB, nullptr, B, H, H,  gx);
    gemm_f16<1, 256><<<g, 512, 0, stream>>>(hB, KW1T, Kb1, p1,     hA, nullptr, B, H, H,  gx);
    gemm_f16<0, 256><<<g, 512, 0, stream>>>(hA, W2T, b2,  nullptr, hB, nullptr, B, H, H,  gx);
    gemm_f16<1, 256><<<g, 512, 0, stream>>>(hB, KW2T, Kb2, p2,     hA, nullptr, B, H, H,  gx);
  }
  {
    int gx = OUT / 128, gy = B / 128;
    dim3 g(gx * gy);
    gemm_f16<2, 128><<<g, 512, 0, stream>>>(hA, W3T, b3, nullptr, nullptr, (float*)d_out, B, OUT, H, gx);
  }
}